// Round 1
// baseline (23093.797 us; speedup 1.0000x reference)
//
#include <hip/hip_runtime.h>
#include <stdint.h>

typedef unsigned short u16;
typedef __attribute__((ext_vector_type(8))) short short8;
typedef __attribute__((ext_vector_type(4))) float f32x4;

#define T_SEQ 1024
#define TP1   1025
#define HDIM  1024
#define NG    3072

__device__ __forceinline__ u16 f2bf(float f) {
  unsigned u = __float_as_uint(f);
  u += 0x7FFF + ((u >> 16) & 1);
  return (u16)(u >> 16);
}
__device__ __forceinline__ float bf2f(u16 h) {
  return __uint_as_float(((unsigned)h) << 16);
}

// async global->LDS, 16B per lane. LDS dest must be wave-uniform base + lane*16.
__device__ __forceinline__ void gld16(void* lds, const void* g) {
  __builtin_amdgcn_global_load_lds(
      (const __attribute__((address_space(1))) unsigned*)g,
      (__attribute__((address_space(3))) unsigned*)lds,
      16, 0, 0);
}

// ---------------- prep: cast 5 weight tensors fp32->bf16, zero barrier counters ----
__global__ void cast5_kernel(const float* __restrict__ s0, const float* __restrict__ s1,
                             const float* __restrict__ s2, const float* __restrict__ s3,
                             const float* __restrict__ s4,
                             u16* __restrict__ d0, u16* __restrict__ d1,
                             u16* __restrict__ d2, u16* __restrict__ d3,
                             u16* __restrict__ d4, unsigned* __restrict__ ctr) {
  if (blockIdx.x == 0 && threadIdx.x < 64) ctr[threadIdx.x] = 0;
  int bid = blockIdx.x;
  const float* s; u16* d; size_t base;
  if (bid < 3072)       { s = s0; d = d0; base = (size_t)bid * 1024; }
  else if (bid < 6144)  { s = s1; d = d1; base = (size_t)(bid - 3072) * 1024; }
  else if (bid < 9216)  { s = s2; d = d2; base = (size_t)(bid - 6144) * 1024; }
  else if (bid < 12288) { s = s3; d = d3; base = (size_t)(bid - 9216) * 1024; }
  else                  { s = s4; d = d4; base = (size_t)(bid - 12288) * 1024; }
  size_t i = base + (size_t)threadIdx.x * 4;
  float4 v = *(const float4*)(s + i);
  unsigned lo = (unsigned)f2bf(v.x) | ((unsigned)f2bf(v.y) << 16);
  unsigned hi = (unsigned)f2bf(v.z) | ((unsigned)f2bf(v.w) << 16);
  uint2 o; o.x = lo; o.y = hi;
  *(uint2*)(d + i) = o;
}

// ---------------- embedding gather + cast to bf16 ------------------------------
__global__ void gather_cast_kernel(const int* __restrict__ tokens,
                                   const float* __restrict__ emb,
                                   u16* __restrict__ xbf) {
  int row = blockIdx.x;                 // 0..16383  (= b*T + t)
  int tok = tokens[row];
  const float4* src = (const float4*)(emb + (size_t)tok * HDIM);
  float4 v = src[threadIdx.x];
  unsigned lo = (unsigned)f2bf(v.x) | ((unsigned)f2bf(v.y) << 16);
  unsigned hi = (unsigned)f2bf(v.z) | ((unsigned)f2bf(v.w) << 16);
  uint2 o; o.x = lo; o.y = hi;
  *(uint2*)(xbf + (size_t)row * HDIM + (size_t)threadIdx.x * 4) = o;
}

// ---------------- bf16 MFMA GEMM, C[m,n] = sum_k A[m,k]*Bt[n,k] -----------------
// 128x128 tile, BK=32, 4 waves each 64x64, global_load_lds width-16 staging (m97 shape).
template <bool OUT_BF16, bool A_REMAP, bool ADD_BIAS>
__global__ __launch_bounds__(256)
void gemm_bt(const u16* __restrict__ A, const u16* __restrict__ Bt,
             void* __restrict__ Cout, const float* __restrict__ bias,
             int M, int N) {
  const int K = 1024;
  __shared__ u16 As[128 * 32];
  __shared__ u16 Bs[128 * 32];
  const int tid = threadIdx.x;
  const int wave = tid >> 6, lane = tid & 63;
  const int quad = lane >> 4, l16 = lane & 15;
  const int wm = (wave & 1) * 64, wn = (wave >> 1) * 64;
  const int m0 = blockIdx.x * 128, n0 = blockIdx.y * 128;
  const int srow = tid >> 2, scol = (tid & 3) * 8;

  size_t arow0, arow1;
  {
    int r0 = m0 + srow, r1 = m0 + 64 + srow;
    if (A_REMAP) {  // logical row b*T+t -> physical row b*(T+1) + t + 1 in hseq
      arow0 = (size_t)((r0 >> 10) * TP1 + (r0 & 1023) + 1);
      arow1 = (size_t)((r1 >> 10) * TP1 + (r1 & 1023) + 1);
    } else { arow0 = (size_t)r0; arow1 = (size_t)r1; }
  }
  const size_t brow0 = (size_t)(n0 + srow), brow1 = (size_t)(n0 + 64 + srow);

  f32x4 acc[4][4] = {};

  for (int kk = 0; kk < K; kk += 32) {
    __syncthreads();  // protect LDS reuse
    gld16(&As[srow * 32 + scol],        A + arow0 * K + kk + scol);
    gld16(&As[(64 + srow) * 32 + scol], A + arow1 * K + kk + scol);
    gld16(&Bs[srow * 32 + scol],        Bt + brow0 * K + kk + scol);
    gld16(&Bs[(64 + srow) * 32 + scol], Bt + brow1 * K + kk + scol);
    __syncthreads();  // compiler drains vmcnt(0) before s_barrier
    short8 af[4], bfr[4];
#pragma unroll
    for (int mt = 0; mt < 4; ++mt)
      af[mt] = *(const short8*)&As[(wm + mt * 16 + l16) * 32 + quad * 8];
#pragma unroll
    for (int nt = 0; nt < 4; ++nt)
      bfr[nt] = *(const short8*)&Bs[(wn + nt * 16 + l16) * 32 + quad * 8];
#pragma unroll
    for (int mt = 0; mt < 4; ++mt)
#pragma unroll
      for (int nt = 0; nt < 4; ++nt)
        acc[mt][nt] = __builtin_amdgcn_mfma_f32_16x16x32_bf16(af[mt], bfr[nt], acc[mt][nt], 0, 0, 0);
  }
#pragma unroll
  for (int mt = 0; mt < 4; ++mt) {
#pragma unroll
    for (int nt = 0; nt < 4; ++nt) {
#pragma unroll
      for (int r = 0; r < 4; ++r) {
        int m = m0 + wm + mt * 16 + quad * 4 + r;   // C row = m (verified layout)
        int n = n0 + wn + nt * 16 + l16;            // C col = n
        float v = acc[mt][nt][r];
        if (ADD_BIAS) v += bias[n];
        if (OUT_BF16) ((u16*)Cout)[(size_t)m * N + n] = f2bf(v);
        else          ((float*)Cout)[(size_t)m * N + n] = v;
      }
    }
  }
}

// ---------------- persistent GRU scan: 64 WGs, grid barrier per step ------------
__global__ __launch_bounds__(256, 1)
void gru_scan_kernel(const u16* __restrict__ gx,     // [B*T, 3072] bf16
                     u16* __restrict__ hseq,         // [B, T+1, H] bf16 (slot 0 = h_{-1})
                     const u16* __restrict__ Whh,    // [3072, 1024] bf16
                     const float* __restrict__ b_ih, const float* __restrict__ b_hh,
                     unsigned* __restrict__ counter) {
  const int tid = threadIdx.x;
  const int wave = tid >> 6, lane = tid & 63;
  const int quad = lane >> 4, l16 = lane & 15;
  const int j0 = blockIdx.x * 16;       // this WG's h-dim slice
  const int kbase = wave * 256;         // K split across 4 waves

  __shared__ u16 hs[16 * 1032];         // h_prev staged, rows padded +8 elems (2-way banks)
  __shared__ float part[4][3][256];     // per-wave K-partials per gate
  __shared__ float biasS[2][3][16];     // [0]=b_ih [1]=b_hh slices

  // W_hh B-fragments resident in registers for the entire scan.
  short8 wf[3][8];
#pragma unroll
  for (int g = 0; g < 3; ++g)
#pragma unroll
    for (int s = 0; s < 8; ++s)
      wf[g][s] = *(const short8*)&Whh[(size_t)(g * 1024 + j0 + l16) * 1024 + kbase + s * 32 + quad * 8];

  if (tid < 96) {
    int a = tid / 48, rem = tid % 48, g = rem >> 4, jl = rem & 15;
    biasS[a][g][jl] = (a ? b_hh : b_ih)[g * 1024 + j0 + jl];
  }
  {  // zero h_{-1} slot (16*1024 elems across 64 WGs * 256 threads)
    int gt = blockIdx.x * 256 + tid;
    int b = gt >> 10, col = gt & 1023;
    hseq[((size_t)b * TP1) * HDIM + col] = 0;
  }
  const int eb = tid >> 4, ej = tid & 15;   // this thread's (batch, j) ownership
  float hprev = 0.f;                        // fp32 recurrent state in-register

  __threadfence();
  __syncthreads();
  unsigned phase = 1;
  if (tid == 0) {
    __hip_atomic_fetch_add(counter, 1, __ATOMIC_RELAXED, __HIP_MEMORY_SCOPE_AGENT);
    while (__hip_atomic_load(counter, __ATOMIC_RELAXED, __HIP_MEMORY_SCOPE_AGENT) < 64u * phase)
      __builtin_amdgcn_s_sleep(2);
  }
  __syncthreads();
  __threadfence();

  for (int t = 0; t < T_SEQ; ++t) {
    // stage h_prev (slot t): 16 rows x 1024 bf16, padded LDS rows
#pragma unroll
    for (int r = 0; r < 8; ++r) {
      int idx = r * 256 + tid;
      int b = idx >> 7, li = idx & 127;
      gld16(&hs[b * 1032 + li * 8], hseq + ((size_t)b * TP1 + t) * HDIM + li * 8);
    }
    // prefetch this thread's gx values (independent of LDS)
    const u16* gxp = gx + ((size_t)(eb * T_SEQ + t)) * NG + j0 + ej;
    u16 gxu0 = gxp[0], gxu1 = gxp[1024], gxu2 = gxp[2048];
    __syncthreads();

    f32x4 acc0 = {0.f, 0.f, 0.f, 0.f}, acc1 = {0.f, 0.f, 0.f, 0.f}, acc2 = {0.f, 0.f, 0.f, 0.f};
#pragma unroll
    for (int s = 0; s < 8; ++s) {
      short8 afr = *(const short8*)&hs[l16 * 1032 + kbase + s * 32 + quad * 8];
      acc0 = __builtin_amdgcn_mfma_f32_16x16x32_bf16(afr, wf[0][s], acc0, 0, 0, 0);
      acc1 = __builtin_amdgcn_mfma_f32_16x16x32_bf16(afr, wf[1][s], acc1, 0, 0, 0);
      acc2 = __builtin_amdgcn_mfma_f32_16x16x32_bf16(afr, wf[2][s], acc2, 0, 0, 0);
    }
#pragma unroll
    for (int r = 0; r < 4; ++r) {
      part[wave][0][(quad * 4 + r) * 16 + l16] = acc0[r];
      part[wave][1][(quad * 4 + r) * 16 + l16] = acc1[r];
      part[wave][2][(quad * 4 + r) * 16 + l16] = acc2[r];
    }
    __syncthreads();

    float ghr = part[0][0][tid] + part[1][0][tid] + part[2][0][tid] + part[3][0][tid] + biasS[1][0][ej];
    float ghz = part[0][1][tid] + part[1][1][tid] + part[2][1][tid] + part[3][1][tid] + biasS[1][1][ej];
    float ghn = part[0][2][tid] + part[1][2][tid] + part[2][2][tid] + part[3][2][tid] + biasS[1][2][ej];
    float xr = bf2f(gxu0) + biasS[0][0][ej] + ghr;
    float xz = bf2f(gxu1) + biasS[0][1][ej] + ghz;
    float xn = bf2f(gxu2) + biasS[0][2][ej];
    float r_ = 1.f / (1.f + __expf(-xr));
    float z_ = 1.f / (1.f + __expf(-xz));
    float pre = xn + r_ * ghn;
    pre = fminf(fmaxf(pre, -15.f), 15.f);
    float e2 = __expf(2.f * pre);
    float n_ = (e2 - 1.f) / (e2 + 1.f);
    float hn = (1.f - z_) * n_ + z_ * hprev;
    hprev = hn;
    hseq[((size_t)eb * TP1 + t + 1) * HDIM + j0 + ej] = f2bf(hn);

    // device-scope barrier (release: wb to L3; acquire: inv L1/L2 — cross-XCD)
    __threadfence();
    __syncthreads();
    ++phase;
    if (tid == 0) {
      __hip_atomic_fetch_add(counter, 1, __ATOMIC_RELAXED, __HIP_MEMORY_SCOPE_AGENT);
      while (__hip_atomic_load(counter, __ATOMIC_RELAXED, __HIP_MEMORY_SCOPE_AGENT) < 64u * phase)
        __builtin_amdgcn_s_sleep(2);
    }
    __syncthreads();
    __threadfence();
  }
}

// ---------------- log_softmax over axis=1 (T), in place on [16,1024,128] --------
__global__ void logsoftmax_kernel(float* __restrict__ out) {
  int b = blockIdx.x;
  int c = threadIdx.x & 127, half = threadIdx.x >> 7;
  float m = -1e30f, s = 0.f;
  for (int t = half; t < T_SEQ; t += 2) {
    float v = out[((size_t)b * T_SEQ + t) * 128 + c];
    if (v > m) { s = s * __expf(m - v) + 1.f; m = v; }
    else s += __expf(v - m);
  }
  __shared__ float mS[256], sS[256];
  mS[threadIdx.x] = m; sS[threadIdx.x] = s;
  __syncthreads();
  if (half == 0) {
    float m2 = mS[threadIdx.x + 128], s2 = sS[threadIdx.x + 128];
    float M = fmaxf(m, m2);
    sS[threadIdx.x] = s * __expf(m - M) + s2 * __expf(m2 - M);
    mS[threadIdx.x] = M;
  }
  __syncthreads();
  float lsd = mS[c] + logf(sS[c]);
  for (int t = half; t < T_SEQ; t += 2) {
    size_t i = ((size_t)b * T_SEQ + t) * 128 + c;
    out[i] = out[i] - lsd;
  }
}

// --------------------------------------------------------------------------------
extern "C" void kernel_launch(void* const* d_in, const int* in_sizes, int n_in,
                              void* d_out, int out_size, void* d_ws, size_t ws_size,
                              hipStream_t stream) {
  const int*   tokens = (const int*)d_in[0];
  const float* emb  = (const float*)d_in[1];
  const float* Wih0 = (const float*)d_in[2];
  const float* Whh0 = (const float*)d_in[3];
  const float* bih0 = (const float*)d_in[4];
  const float* bhh0 = (const float*)d_in[5];
  const float* Wih1 = (const float*)d_in[6];
  const float* Whh1 = (const float*)d_in[7];
  const float* bih1 = (const float*)d_in[8];
  const float* bhh1 = (const float*)d_in[9];
  const float* Wlin = (const float*)d_in[10];
  const float* blin = (const float*)d_in[11];
  float* out = (float*)d_out;

  uint8_t* ws = (uint8_t*)d_ws;
  size_t off = 0;
  auto alloc = [&](size_t bytes) -> void* {
    void* p = ws + off;
    off += (bytes + 255) & ~(size_t)255;
    return p;
  };
  u16* h1seq = (u16*)alloc((size_t)16 * TP1 * HDIM * 2);  // also holds x_bf (plain layout) pre-scan
  u16* h2seq = (u16*)alloc((size_t)16 * TP1 * HDIM * 2);
  u16* gxbuf = (u16*)alloc((size_t)16384 * NG * 2);       // reused for both layers
  u16* wih0b = (u16*)alloc((size_t)NG * HDIM * 2);
  u16* whh0b = (u16*)alloc((size_t)NG * HDIM * 2);
  u16* wih1b = (u16*)alloc((size_t)NG * HDIM * 2);
  u16* whh1b = (u16*)alloc((size_t)NG * HDIM * 2);
  u16* wlinb = (u16*)alloc((size_t)128 * HDIM * 2);
  unsigned* ctr = (unsigned*)alloc(256);

  cast5_kernel<<<dim3(12416), dim3(256), 0, stream>>>(
      Wih0, Whh0, Wih1, Whh1, Wlin, wih0b, whh0b, wih1b, whh1b, wlinb, ctr);
  gather_cast_kernel<<<dim3(16384), dim3(256), 0, stream>>>(tokens, emb, h1seq);
  // gx0 = x @ W_ih0^T
  gemm_bt<true, false, false><<<dim3(128, 24), dim3(256), 0, stream>>>(
      h1seq, wih0b, gxbuf, nullptr, 16384, NG);
  // layer-0 scan -> h1seq [(b, t+1)] (overwrites x region; x is dead)
  gru_scan_kernel<<<dim3(64), dim3(256), 0, stream>>>(gxbuf, h1seq, whh0b, bih0, bhh0, ctr);
  // gx1 = h1 @ W_ih1^T (row remap into (T+1)-strided h1seq)
  gemm_bt<true, true, false><<<dim3(128, 24), dim3(256), 0, stream>>>(
      h1seq, wih1b, gxbuf, nullptr, 16384, NG);
  // layer-1 scan -> h2seq
  gru_scan_kernel<<<dim3(64), dim3(256), 0, stream>>>(gxbuf, h2seq, whh1b, bih1, bhh1, ctr + 32);
  // logits = h2 @ W_lin^T + b_lin -> d_out (fp32)
  gemm_bt<false, true, true><<<dim3(128, 1), dim3(256), 0, stream>>>(
      h2seq, wlinb, out, blin, 16384, 128);
  // log_softmax over T, in place
  logsoftmax_kernel<<<dim3(16), dim3(256), 0, stream>>>(out);
}

// Round 2
// 6233.836 us; speedup vs baseline: 3.7046x; 3.7046x over previous
//
#include <hip/hip_runtime.h>
#include <stdint.h>

typedef unsigned short u16;
typedef __attribute__((ext_vector_type(8))) short short8;
typedef __attribute__((ext_vector_type(4))) float f32x4;

#define T_SEQ 1024
#define TP1   1025
#define HDIM  1024
#define NG    3072

__device__ __forceinline__ u16 f2bf(float f) {
  unsigned u = __float_as_uint(f);
  u += 0x7FFF + ((u >> 16) & 1);
  return (u16)(u >> 16);
}
__device__ __forceinline__ float bf2f(u16 h) {
  return __uint_as_float(((unsigned)h) << 16);
}

// async global->LDS, 16B per lane. LDS dest must be wave-uniform base + lane*16.
__device__ __forceinline__ void gld16(void* lds, const void* g) {
  __builtin_amdgcn_global_load_lds(
      (const __attribute__((address_space(1))) unsigned*)g,
      (__attribute__((address_space(3))) unsigned*)lds,
      16, 0, 0);
}

// ---------------- prep: cast 5 weight tensors fp32->bf16, zero barrier flags ----
__global__ void cast5_kernel(const float* __restrict__ s0, const float* __restrict__ s1,
                             const float* __restrict__ s2, const float* __restrict__ s3,
                             const float* __restrict__ s4,
                             u16* __restrict__ d0, u16* __restrict__ d1,
                             u16* __restrict__ d2, u16* __restrict__ d3,
                             u16* __restrict__ d4, unsigned* __restrict__ flags) {
  if (blockIdx.x == 0) {
#pragma unroll
    for (int k = 0; k < 8; ++k) flags[threadIdx.x * 8 + k] = 0;  // 8 KB of flags
  }
  int bid = blockIdx.x;
  const float* s; u16* d; size_t base;
  if (bid < 3072)       { s = s0; d = d0; base = (size_t)bid * 1024; }
  else if (bid < 6144)  { s = s1; d = d1; base = (size_t)(bid - 3072) * 1024; }
  else if (bid < 9216)  { s = s2; d = d2; base = (size_t)(bid - 6144) * 1024; }
  else if (bid < 12288) { s = s3; d = d3; base = (size_t)(bid - 9216) * 1024; }
  else                  { s = s4; d = d4; base = (size_t)(bid - 12288) * 1024; }
  size_t i = base + (size_t)threadIdx.x * 4;
  float4 v = *(const float4*)(s + i);
  unsigned lo = (unsigned)f2bf(v.x) | ((unsigned)f2bf(v.y) << 16);
  unsigned hi = (unsigned)f2bf(v.z) | ((unsigned)f2bf(v.w) << 16);
  uint2 o; o.x = lo; o.y = hi;
  *(uint2*)(d + i) = o;
}

// ---------------- embedding gather + cast to bf16 ------------------------------
__global__ void gather_cast_kernel(const int* __restrict__ tokens,
                                   const float* __restrict__ emb,
                                   u16* __restrict__ xbf) {
  int row = blockIdx.x;                 // 0..16383  (= b*T + t)
  int tok = tokens[row];
  const float4* src = (const float4*)(emb + (size_t)tok * HDIM);
  float4 v = src[threadIdx.x];
  unsigned lo = (unsigned)f2bf(v.x) | ((unsigned)f2bf(v.y) << 16);
  unsigned hi = (unsigned)f2bf(v.z) | ((unsigned)f2bf(v.w) << 16);
  uint2 o; o.x = lo; o.y = hi;
  *(uint2*)(xbf + (size_t)row * HDIM + (size_t)threadIdx.x * 4) = o;
}

// ---------------- bf16 MFMA GEMM, C[m,n] = sum_k A[m,k]*Bt[n,k] -----------------
template <bool OUT_BF16, bool A_REMAP, bool ADD_BIAS>
__global__ __launch_bounds__(256)
void gemm_bt(const u16* __restrict__ A, const u16* __restrict__ Bt,
             void* __restrict__ Cout, const float* __restrict__ bias,
             int M, int N) {
  const int K = 1024;
  __shared__ u16 As[128 * 32];
  __shared__ u16 Bs[128 * 32];
  const int tid = threadIdx.x;
  const int wave = tid >> 6, lane = tid & 63;
  const int quad = lane >> 4, l16 = lane & 15;
  const int wm = (wave & 1) * 64, wn = (wave >> 1) * 64;
  const int m0 = blockIdx.x * 128, n0 = blockIdx.y * 128;
  const int srow = tid >> 2, scol = (tid & 3) * 8;

  size_t arow0, arow1;
  {
    int r0 = m0 + srow, r1 = m0 + 64 + srow;
    if (A_REMAP) {  // logical row b*T+t -> physical row b*(T+1) + t + 1 in hseq
      arow0 = (size_t)((r0 >> 10) * TP1 + (r0 & 1023) + 1);
      arow1 = (size_t)((r1 >> 10) * TP1 + (r1 & 1023) + 1);
    } else { arow0 = (size_t)r0; arow1 = (size_t)r1; }
  }
  const size_t brow0 = (size_t)(n0 + srow), brow1 = (size_t)(n0 + 64 + srow);

  f32x4 acc[4][4] = {};

  for (int kk = 0; kk < K; kk += 32) {
    __syncthreads();
    gld16(&As[srow * 32 + scol],        A + arow0 * K + kk + scol);
    gld16(&As[(64 + srow) * 32 + scol], A + arow1 * K + kk + scol);
    gld16(&Bs[srow * 32 + scol],        Bt + brow0 * K + kk + scol);
    gld16(&Bs[(64 + srow) * 32 + scol], Bt + brow1 * K + kk + scol);
    __syncthreads();
    short8 af[4], bfr[4];
#pragma unroll
    for (int mt = 0; mt < 4; ++mt)
      af[mt] = *(const short8*)&As[(wm + mt * 16 + l16) * 32 + quad * 8];
#pragma unroll
    for (int nt = 0; nt < 4; ++nt)
      bfr[nt] = *(const short8*)&Bs[(wn + nt * 16 + l16) * 32 + quad * 8];
#pragma unroll
    for (int mt = 0; mt < 4; ++mt)
#pragma unroll
      for (int nt = 0; nt < 4; ++nt)
        acc[mt][nt] = __builtin_amdgcn_mfma_f32_16x16x32_bf16(af[mt], bfr[nt], acc[mt][nt], 0, 0, 0);
  }
#pragma unroll
  for (int mt = 0; mt < 4; ++mt) {
#pragma unroll
    for (int nt = 0; nt < 4; ++nt) {
#pragma unroll
      for (int r = 0; r < 4; ++r) {
        int m = m0 + wm + mt * 16 + quad * 4 + r;
        int n = n0 + wn + nt * 16 + l16;
        float v = acc[mt][nt][r];
        if (ADD_BIAS) v += bias[n];
        if (OUT_BF16) ((u16*)Cout)[(size_t)m * N + n] = f2bf(v);
        else          ((float*)Cout)[(size_t)m * N + n] = v;
      }
    }
  }
}

// ---------------- persistent GRU scan: 64 WGs, fence-free grid barrier ----------
// Correctness model: every hseq slot (b,t) is written exactly once (agent-scope
// write-through -> visible at the memory-side Infinity Cache) and first read only
// after the producer's RELEASE flag store is observed; readers have no stale
// copies (lines never touched before), so no acquire/invalidate is needed.
__global__ __launch_bounds__(256, 1)
void gru_scan_kernel(const u16* __restrict__ gx,     // [B*T, 3072] bf16
                     u16* __restrict__ hseq,         // [B, T+1, H] bf16 (slot 0 = h_{-1})
                     const u16* __restrict__ Whh,    // [3072, 1024] bf16
                     const float* __restrict__ b_ih, const float* __restrict__ b_hh,
                     unsigned* __restrict__ flags) { // 64 flags, stride 16 u32 (64 B)
  const int tid = threadIdx.x;
  const int wave = tid >> 6, lane = tid & 63;
  const int quad = lane >> 4, l16 = lane & 15;
  const int j0 = blockIdx.x * 16;       // this WG's h-dim slice
  const int kbase = wave * 256;         // K split across 4 waves

  __shared__ u16 hs[16 * 1032];         // h_prev staged, rows padded +8 elems
  __shared__ float part[4][3][256];     // per-wave K-partials per gate
  __shared__ float biasS[2][3][16];

  // W_hh B-fragments resident in registers for the entire scan.
  short8 wf[3][8];
#pragma unroll
  for (int g = 0; g < 3; ++g)
#pragma unroll
    for (int s = 0; s < 8; ++s)
      wf[g][s] = *(const short8*)&Whh[(size_t)(g * 1024 + j0 + l16) * 1024 + kbase + s * 32 + quad * 8];

  if (tid < 96) {
    int a = tid / 48, rem = tid % 48, g = rem >> 4, jl = rem & 15;
    biasS[a][g][jl] = (a ? b_hh : b_ih)[g * 1024 + j0 + jl];
  }
  {  // zero h_{-1} slot with agent-scope (write-through) stores
    int gt = blockIdx.x * 256 + tid;    // 0..16383; need 8192 u32 stores
    if (gt < 8192) {
      int b = gt >> 9, half = gt & 511;
      unsigned* p = (unsigned*)(hseq + ((size_t)b * TP1) * HDIM) + half;
      __hip_atomic_store(p, 0u, __ATOMIC_RELAXED, __HIP_MEMORY_SCOPE_AGENT);
    }
  }
  const int eb = tid >> 4, ej = tid & 15;   // this thread's (batch, j) ownership
  float hprev = 0.f;                        // fp32 recurrent state in-register

  unsigned phase = 1;
  __syncthreads();  // drains this WG's zero stores (vmcnt(0) before s_barrier)
  if (tid == 0)
    __hip_atomic_store(&flags[blockIdx.x * 16], phase, __ATOMIC_RELEASE, __HIP_MEMORY_SCOPE_AGENT);
  if (wave == 0) {
    for (;;) {
      unsigned v = __hip_atomic_load(&flags[lane * 16], __ATOMIC_RELAXED, __HIP_MEMORY_SCOPE_AGENT);
      if (__ballot(v >= phase) == ~0ull) break;
      __builtin_amdgcn_s_sleep(1);
    }
  }
  __syncthreads();

  for (int t = 0; t < T_SEQ; ++t) {
    // stage h[t] (32 KB) via async global->LDS; lines are fresh (never cached stale)
#pragma unroll
    for (int r = 0; r < 8; ++r) {
      int idx = r * 256 + tid;
      int b = idx >> 7, li = idx & 127;
      gld16(&hs[b * 1032 + li * 8], hseq + ((size_t)b * TP1 + t) * HDIM + li * 8);
    }
    // prefetch this thread's gx values (independent of LDS)
    const u16* gxp = gx + ((size_t)(eb * T_SEQ + t)) * NG + j0 + ej;
    u16 gxu0 = gxp[0], gxu1 = gxp[1024], gxu2 = gxp[2048];
    __syncthreads();

    f32x4 acc0 = {0.f, 0.f, 0.f, 0.f}, acc1 = {0.f, 0.f, 0.f, 0.f}, acc2 = {0.f, 0.f, 0.f, 0.f};
#pragma unroll
    for (int s = 0; s < 8; ++s) {
      short8 afr = *(const short8*)&hs[l16 * 1032 + kbase + s * 32 + quad * 8];
      acc0 = __builtin_amdgcn_mfma_f32_16x16x32_bf16(afr, wf[0][s], acc0, 0, 0, 0);
      acc1 = __builtin_amdgcn_mfma_f32_16x16x32_bf16(afr, wf[1][s], acc1, 0, 0, 0);
      acc2 = __builtin_amdgcn_mfma_f32_16x16x32_bf16(afr, wf[2][s], acc2, 0, 0, 0);
    }
#pragma unroll
    for (int r = 0; r < 4; ++r) {
      part[wave][0][(quad * 4 + r) * 16 + l16] = acc0[r];
      part[wave][1][(quad * 4 + r) * 16 + l16] = acc1[r];
      part[wave][2][(quad * 4 + r) * 16 + l16] = acc2[r];
    }
    __syncthreads();

    float ghr = part[0][0][tid] + part[1][0][tid] + part[2][0][tid] + part[3][0][tid] + biasS[1][0][ej];
    float ghz = part[0][1][tid] + part[1][1][tid] + part[2][1][tid] + part[3][1][tid] + biasS[1][1][ej];
    float ghn = part[0][2][tid] + part[1][2][tid] + part[2][2][tid] + part[3][2][tid] + biasS[1][2][ej];
    float xr = bf2f(gxu0) + biasS[0][0][ej] + ghr;
    float xz = bf2f(gxu1) + biasS[0][1][ej] + ghz;
    float xn = bf2f(gxu2) + biasS[0][2][ej];
    float r_ = 1.f / (1.f + __expf(-xr));
    float z_ = 1.f / (1.f + __expf(-xz));
    float pre = xn + r_ * ghn;
    pre = fminf(fmaxf(pre, -15.f), 15.f);
    float e2 = __expf(2.f * pre);
    float n_ = (e2 - 1.f) / (e2 + 1.f);
    float hn = (1.f - z_) * n_ + z_ * hprev;
    hprev = hn;

    // pair-pack two bf16 and write-through (agent scope, no dirty L2 lines)
    unsigned mine = (unsigned)f2bf(hn);
    unsigned other = __shfl_xor(mine, 1);
    if ((tid & 1) == 0) {
      unsigned pk = mine | (other << 16);
      unsigned* p = (unsigned*)(hseq + ((size_t)eb * TP1 + t + 1) * HDIM + j0 + ej);
      __hip_atomic_store(p, pk, __ATOMIC_RELAXED, __HIP_MEMORY_SCOPE_AGENT);
    }

    ++phase;
    __syncthreads();  // drains h stores (compiler emits vmcnt(0) before s_barrier)
    if (tid == 0)
      __hip_atomic_store(&flags[blockIdx.x * 16], phase, __ATOMIC_RELEASE, __HIP_MEMORY_SCOPE_AGENT);
    if (wave == 0) {
      for (;;) {
        unsigned v = __hip_atomic_load(&flags[lane * 16], __ATOMIC_RELAXED, __HIP_MEMORY_SCOPE_AGENT);
        if (__ballot(v >= phase) == ~0ull) break;
        __builtin_amdgcn_s_sleep(1);
      }
    }
    __syncthreads();
  }
}

// ---------------- log_softmax over axis=1 (T), in place on [16,1024,128] --------
__global__ void logsoftmax_kernel(float* __restrict__ out) {
  int b = blockIdx.x;
  int c = threadIdx.x & 127, half = threadIdx.x >> 7;
  float m = -1e30f, s = 0.f;
  for (int t = half; t < T_SEQ; t += 2) {
    float v = out[((size_t)b * T_SEQ + t) * 128 + c];
    if (v > m) { s = s * __expf(m - v) + 1.f; m = v; }
    else s += __expf(v - m);
  }
  __shared__ float mS[256], sS[256];
  mS[threadIdx.x] = m; sS[threadIdx.x] = s;
  __syncthreads();
  if (half == 0) {
    float m2 = mS[threadIdx.x + 128], s2 = sS[threadIdx.x + 128];
    float M = fmaxf(m, m2);
    sS[threadIdx.x] = s * __expf(m - M) + s2 * __expf(m2 - M);
    mS[threadIdx.x] = M;
  }
  __syncthreads();
  float lsd = mS[c] + logf(sS[c]);
  for (int t = half; t < T_SEQ; t += 2) {
    size_t i = ((size_t)b * T_SEQ + t) * 128 + c;
    out[i] = out[i] - lsd;
  }
}

// --------------------------------------------------------------------------------
extern "C" void kernel_launch(void* const* d_in, const int* in_sizes, int n_in,
                              void* d_out, int out_size, void* d_ws, size_t ws_size,
                              hipStream_t stream) {
  const int*   tokens = (const int*)d_in[0];
  const float* emb  = (const float*)d_in[1];
  const float* Wih0 = (const float*)d_in[2];
  const float* Whh0 = (const float*)d_in[3];
  const float* bih0 = (const float*)d_in[4];
  const float* bhh0 = (const float*)d_in[5];
  const float* Wih1 = (const float*)d_in[6];
  const float* Whh1 = (const float*)d_in[7];
  const float* bih1 = (const float*)d_in[8];
  const float* bhh1 = (const float*)d_in[9];
  const float* Wlin = (const float*)d_in[10];
  const float* blin = (const float*)d_in[11];
  float* out = (float*)d_out;

  uint8_t* ws = (uint8_t*)d_ws;
  size_t off = 0;
  auto alloc = [&](size_t bytes) -> void* {
    void* p = ws + off;
    off += (bytes + 255) & ~(size_t)255;
    return p;
  };
  u16* h1seq = (u16*)alloc((size_t)16 * TP1 * HDIM * 2);  // also holds x_bf pre-scan
  u16* h2seq = (u16*)alloc((size_t)16 * TP1 * HDIM * 2);
  u16* gxbuf = (u16*)alloc((size_t)16384 * NG * 2);       // reused for both layers
  u16* wih0b = (u16*)alloc((size_t)NG * HDIM * 2);
  u16* whh0b = (u16*)alloc((size_t)NG * HDIM * 2);
  u16* wih1b = (u16*)alloc((size_t)NG * HDIM * 2);
  u16* whh1b = (u16*)alloc((size_t)NG * HDIM * 2);
  u16* wlinb = (u16*)alloc((size_t)128 * HDIM * 2);
  unsigned* flags = (unsigned*)alloc(8192);   // 2 scans x 64 flags x 64 B stride

  cast5_kernel<<<dim3(12416), dim3(256), 0, stream>>>(
      Wih0, Whh0, Wih1, Whh1, Wlin, wih0b, whh0b, wih1b, whh1b, wlinb, flags);
  gather_cast_kernel<<<dim3(16384), dim3(256), 0, stream>>>(tokens, emb, h1seq);
  // gx0 = x @ W_ih0^T
  gemm_bt<true, false, false><<<dim3(128, 24), dim3(256), 0, stream>>>(
      h1seq, wih0b, gxbuf, nullptr, 16384, NG);
  // layer-0 scan -> h1seq [(b, t+1)]
  gru_scan_kernel<<<dim3(64), dim3(256), 0, stream>>>(gxbuf, h1seq, whh0b, bih0, bhh0, flags);
  // gx1 = h1 @ W_ih1^T (row remap into (T+1)-strided h1seq)
  gemm_bt<true, true, false><<<dim3(128, 24), dim3(256), 0, stream>>>(
      h1seq, wih1b, gxbuf, nullptr, 16384, NG);
  // layer-1 scan -> h2seq
  gru_scan_kernel<<<dim3(64), dim3(256), 0, stream>>>(gxbuf, h2seq, whh1b, bih1, bhh1, flags + 1024);
  // logits = h2 @ W_lin^T + b_lin -> d_out (fp32)
  gemm_bt<false, true, true><<<dim3(128, 1), dim3(256), 0, stream>>>(
      h2seq, wlinb, out, blin, 16384, 128);
  // log_softmax over T, in place
  logsoftmax_kernel<<<dim3(16), dim3(256), 0, stream>>>(out);
}

// Round 3
// 4591.012 us; speedup vs baseline: 5.0302x; 1.3578x over previous
//
#include <hip/hip_runtime.h>
#include <stdint.h>

typedef unsigned short u16;
typedef __attribute__((ext_vector_type(8))) short short8;
typedef __attribute__((ext_vector_type(4))) float f32x4;

#define T_SEQ 1024
#define TP1   1025
#define HDIM  1024
#define NG    3072

__device__ __forceinline__ u16 f2bf(float f) {
  unsigned u = __float_as_uint(f);
  u += 0x7FFF + ((u >> 16) & 1);
  return (u16)(u >> 16);
}
__device__ __forceinline__ float bf2f(u16 h) {
  return __uint_as_float(((unsigned)h) << 16);
}

// async global->LDS, 16B per lane. LDS dest must be wave-uniform base + lane*16.
__device__ __forceinline__ void gld16(void* lds, const void* g) {
  __builtin_amdgcn_global_load_lds(
      (const __attribute__((address_space(1))) unsigned*)g,
      (__attribute__((address_space(3))) unsigned*)lds,
      16, 0, 0);
}

// ---------------- prep: cast 5 weight tensors fp32->bf16, zero barrier flags ----
__global__ void cast5_kernel(const float* __restrict__ s0, const float* __restrict__ s1,
                             const float* __restrict__ s2, const float* __restrict__ s3,
                             const float* __restrict__ s4,
                             u16* __restrict__ d0, u16* __restrict__ d1,
                             u16* __restrict__ d2, u16* __restrict__ d3,
                             u16* __restrict__ d4, unsigned* __restrict__ flags) {
  if (blockIdx.x == 0) {
#pragma unroll
    for (int k = 0; k < 8; ++k) flags[threadIdx.x * 8 + k] = 0;  // 8 KB of flags
  }
  int bid = blockIdx.x;
  const float* s; u16* d; size_t base;
  if (bid < 3072)       { s = s0; d = d0; base = (size_t)bid * 1024; }
  else if (bid < 6144)  { s = s1; d = d1; base = (size_t)(bid - 3072) * 1024; }
  else if (bid < 9216)  { s = s2; d = d2; base = (size_t)(bid - 6144) * 1024; }
  else if (bid < 12288) { s = s3; d = d3; base = (size_t)(bid - 9216) * 1024; }
  else                  { s = s4; d = d4; base = (size_t)(bid - 12288) * 1024; }
  size_t i = base + (size_t)threadIdx.x * 4;
  float4 v = *(const float4*)(s + i);
  unsigned lo = (unsigned)f2bf(v.x) | ((unsigned)f2bf(v.y) << 16);
  unsigned hi = (unsigned)f2bf(v.z) | ((unsigned)f2bf(v.w) << 16);
  uint2 o; o.x = lo; o.y = hi;
  *(uint2*)(d + i) = o;
}

// ---------------- embedding gather + cast to bf16 ------------------------------
__global__ void gather_cast_kernel(const int* __restrict__ tokens,
                                   const float* __restrict__ emb,
                                   u16* __restrict__ xbf) {
  int row = blockIdx.x;                 // 0..16383  (= b*T + t)
  int tok = tokens[row];
  const float4* src = (const float4*)(emb + (size_t)tok * HDIM);
  float4 v = src[threadIdx.x];
  unsigned lo = (unsigned)f2bf(v.x) | ((unsigned)f2bf(v.y) << 16);
  unsigned hi = (unsigned)f2bf(v.z) | ((unsigned)f2bf(v.w) << 16);
  uint2 o; o.x = lo; o.y = hi;
  *(uint2*)(xbf + (size_t)row * HDIM + (size_t)threadIdx.x * 4) = o;
}

// ---------------- bf16 MFMA GEMM, C[m,n] = sum_k A[m,k]*Bt[n,k] -----------------
template <bool OUT_BF16, bool A_REMAP, bool ADD_BIAS>
__global__ __launch_bounds__(256)
void gemm_bt(const u16* __restrict__ A, const u16* __restrict__ Bt,
             void* __restrict__ Cout, const float* __restrict__ bias,
             int M, int N) {
  const int K = 1024;
  __shared__ u16 As[128 * 32];
  __shared__ u16 Bs[128 * 32];
  const int tid = threadIdx.x;
  const int wave = tid >> 6, lane = tid & 63;
  const int quad = lane >> 4, l16 = lane & 15;
  const int wm = (wave & 1) * 64, wn = (wave >> 1) * 64;
  const int m0 = blockIdx.x * 128, n0 = blockIdx.y * 128;
  const int srow = tid >> 2, scol = (tid & 3) * 8;

  size_t arow0, arow1;
  {
    int r0 = m0 + srow, r1 = m0 + 64 + srow;
    if (A_REMAP) {  // logical row b*T+t -> physical row b*(T+1) + t + 1 in hseq
      arow0 = (size_t)((r0 >> 10) * TP1 + (r0 & 1023) + 1);
      arow1 = (size_t)((r1 >> 10) * TP1 + (r1 & 1023) + 1);
    } else { arow0 = (size_t)r0; arow1 = (size_t)r1; }
  }
  const size_t brow0 = (size_t)(n0 + srow), brow1 = (size_t)(n0 + 64 + srow);

  f32x4 acc[4][4] = {};

  for (int kk = 0; kk < K; kk += 32) {
    __syncthreads();
    gld16(&As[srow * 32 + scol],        A + arow0 * K + kk + scol);
    gld16(&As[(64 + srow) * 32 + scol], A + arow1 * K + kk + scol);
    gld16(&Bs[srow * 32 + scol],        Bt + brow0 * K + kk + scol);
    gld16(&Bs[(64 + srow) * 32 + scol], Bt + brow1 * K + kk + scol);
    __syncthreads();
    short8 af[4], bfr[4];
#pragma unroll
    for (int mt = 0; mt < 4; ++mt)
      af[mt] = *(const short8*)&As[(wm + mt * 16 + l16) * 32 + quad * 8];
#pragma unroll
    for (int nt = 0; nt < 4; ++nt)
      bfr[nt] = *(const short8*)&Bs[(wn + nt * 16 + l16) * 32 + quad * 8];
#pragma unroll
    for (int mt = 0; mt < 4; ++mt)
#pragma unroll
      for (int nt = 0; nt < 4; ++nt)
        acc[mt][nt] = __builtin_amdgcn_mfma_f32_16x16x32_bf16(af[mt], bfr[nt], acc[mt][nt], 0, 0, 0);
  }
#pragma unroll
  for (int mt = 0; mt < 4; ++mt) {
#pragma unroll
    for (int nt = 0; nt < 4; ++nt) {
#pragma unroll
      for (int r = 0; r < 4; ++r) {
        int m = m0 + wm + mt * 16 + quad * 4 + r;
        int n = n0 + wn + nt * 16 + l16;
        float v = acc[mt][nt][r];
        if (ADD_BIAS) v += bias[n];
        if (OUT_BF16) ((u16*)Cout)[(size_t)m * N + n] = f2bf(v);
        else          ((float*)Cout)[(size_t)m * N + n] = v;
      }
    }
  }
}

// ---------------- fused 2-layer persistent GRU scan, 128 WGs --------------------
// WGs 0..63: layer 0 (gx0 precomputed). WGs 64..127: layer 1, one step behind,
// computing gx1 = h1[t] @ Wih1^T on the fly (both weight slices register-resident).
// Fence-free sync: agent-scope write-through h stores + RELEASE flag per WG;
// readers never hold stale copies of h lines (each slot written once, read after).
__global__ __launch_bounds__(256, 1)
void fused_scan_kernel(const u16* __restrict__ gx0,
                       u16* __restrict__ h1seq, u16* __restrict__ h2seq,
                       const u16* __restrict__ Whh0, const u16* __restrict__ Wih1,
                       const u16* __restrict__ Whh1,
                       const float* __restrict__ bih0, const float* __restrict__ bhh0,
                       const float* __restrict__ bih1, const float* __restrict__ bhh1,
                       unsigned* __restrict__ flags0, unsigned* __restrict__ flags1) {
  const int tid = threadIdx.x;
  const int wave = tid >> 6, lane = tid & 63;
  const int quad = lane >> 4, l16 = lane & 15;
  const int kbase = wave * 256;         // K split across 4 waves
  const int eb = tid >> 4, ej = tid & 15;

  __shared__ u16 hsA[16 * 1032];        // padded rows (+8 elems)
  __shared__ u16 hsB[16 * 1032];        // layer-1 only: h2 staging
  __shared__ float part[4][6][256];
  __shared__ float biasS[2][3][16];

  if (blockIdx.x < 64) {
    // ======================= LAYER 0 =======================
    const int wg = blockIdx.x, j0 = wg * 16;
    short8 wf[3][8];
#pragma unroll
    for (int g = 0; g < 3; ++g)
#pragma unroll
      for (int s = 0; s < 8; ++s)
        wf[g][s] = *(const short8*)&Whh0[(size_t)(g * 1024 + j0 + l16) * 1024 + kbase + s * 32 + quad * 8];
    if (tid < 96) {
      int a = tid / 48, rem = tid % 48, g = rem >> 4, jl = rem & 15;
      biasS[a][g][jl] = (a ? bhh0 : bih0)[g * 1024 + j0 + jl];
    }
    {  // zero h1 slot 0 (agent-scope write-through)
      int gt = wg * 256 + tid;
      if (gt < 8192) {
        int b = gt >> 9, half = gt & 511;
        __hip_atomic_store((unsigned*)(h1seq + ((size_t)b * TP1) * HDIM) + half, 0u,
                           __ATOMIC_RELAXED, __HIP_MEMORY_SCOPE_AGENT);
      }
    }
    float hprev = 0.f;
    unsigned phase = 1;
    __syncthreads();  // drain zero stores
    if (tid == 0)
      __hip_atomic_store(&flags0[wg * 16], phase, __ATOMIC_RELEASE, __HIP_MEMORY_SCOPE_AGENT);
    if (wave == 0)
      for (;;) {
        unsigned v = __hip_atomic_load(&flags0[lane * 16], __ATOMIC_RELAXED, __HIP_MEMORY_SCOPE_AGENT);
        if (__ballot(v >= phase) == ~0ull) break;
      }
    __syncthreads();

    for (int t = 0; t < T_SEQ; ++t) {
#pragma unroll
      for (int r = 0; r < 8; ++r) {
        int idx = r * 256 + tid;
        int b = idx >> 7, li = idx & 127;
        gld16(&hsA[b * 1032 + li * 8], h1seq + ((size_t)b * TP1 + t) * HDIM + li * 8);
      }
      const u16* gxp = gx0 + ((size_t)(eb * T_SEQ + t)) * NG + j0 + ej;
      u16 gxu0 = gxp[0], gxu1 = gxp[1024], gxu2 = gxp[2048];
      __syncthreads();

      f32x4 a0 = {0.f,0.f,0.f,0.f}, a1 = {0.f,0.f,0.f,0.f}, a2 = {0.f,0.f,0.f,0.f};
#pragma unroll
      for (int s = 0; s < 8; ++s) {
        short8 afr = *(const short8*)&hsA[l16 * 1032 + kbase + s * 32 + quad * 8];
        a0 = __builtin_amdgcn_mfma_f32_16x16x32_bf16(afr, wf[0][s], a0, 0, 0, 0);
        a1 = __builtin_amdgcn_mfma_f32_16x16x32_bf16(afr, wf[1][s], a1, 0, 0, 0);
        a2 = __builtin_amdgcn_mfma_f32_16x16x32_bf16(afr, wf[2][s], a2, 0, 0, 0);
      }
#pragma unroll
      for (int r = 0; r < 4; ++r) {
        part[wave][0][(quad * 4 + r) * 16 + l16] = a0[r];
        part[wave][1][(quad * 4 + r) * 16 + l16] = a1[r];
        part[wave][2][(quad * 4 + r) * 16 + l16] = a2[r];
      }
      __syncthreads();

      float ghr = part[0][0][tid] + part[1][0][tid] + part[2][0][tid] + part[3][0][tid] + biasS[1][0][ej];
      float ghz = part[0][1][tid] + part[1][1][tid] + part[2][1][tid] + part[3][1][tid] + biasS[1][1][ej];
      float ghn = part[0][2][tid] + part[1][2][tid] + part[2][2][tid] + part[3][2][tid] + biasS[1][2][ej];
      float xr = bf2f(gxu0) + biasS[0][0][ej] + ghr;
      float xz = bf2f(gxu1) + biasS[0][1][ej] + ghz;
      float xn = bf2f(gxu2) + biasS[0][2][ej];
      float r_ = 1.f / (1.f + __expf(-xr));
      float z_ = 1.f / (1.f + __expf(-xz));
      float pre = fminf(fmaxf(xn + r_ * ghn, -15.f), 15.f);
      float e2 = __expf(2.f * pre);
      float n_ = (e2 - 1.f) / (e2 + 1.f);
      float hn = (1.f - z_) * n_ + z_ * hprev;
      hprev = hn;

      unsigned mine = (unsigned)f2bf(hn);
      unsigned other = __shfl_xor(mine, 1);
      if ((tid & 1) == 0) {
        unsigned pk = mine | (other << 16);
        __hip_atomic_store((unsigned*)(h1seq + ((size_t)eb * TP1 + t + 1) * HDIM + j0 + ej), pk,
                           __ATOMIC_RELAXED, __HIP_MEMORY_SCOPE_AGENT);
      }
      ++phase;
      __syncthreads();  // drain h stores
      if (tid == 0)
        __hip_atomic_store(&flags0[wg * 16], phase, __ATOMIC_RELEASE, __HIP_MEMORY_SCOPE_AGENT);
      if (wave == 0)
        for (;;) {
          unsigned v = __hip_atomic_load(&flags0[lane * 16], __ATOMIC_RELAXED, __HIP_MEMORY_SCOPE_AGENT);
          if (__ballot(v >= phase) == ~0ull) break;
        }
      __syncthreads();
    }
  } else {
    // ======================= LAYER 1 =======================
    const int wg = blockIdx.x - 64, j0 = wg * 16;
    short8 wfX[3][8], wfH[3][8];
#pragma unroll
    for (int g = 0; g < 3; ++g)
#pragma unroll
      for (int s = 0; s < 8; ++s) {
        size_t row = (size_t)(g * 1024 + j0 + l16) * 1024 + kbase + s * 32 + quad * 8;
        wfX[g][s] = *(const short8*)&Wih1[row];
        wfH[g][s] = *(const short8*)&Whh1[row];
      }
    if (tid < 96) {
      int a = tid / 48, rem = tid % 48, g = rem >> 4, jl = rem & 15;
      biasS[a][g][jl] = (a ? bhh1 : bih1)[g * 1024 + j0 + jl];
    }
    {  // zero h2 slot 0
      int gt = wg * 256 + tid;
      if (gt < 8192) {
        int b = gt >> 9, half = gt & 511;
        __hip_atomic_store((unsigned*)(h2seq + ((size_t)b * TP1) * HDIM) + half, 0u,
                           __ATOMIC_RELAXED, __HIP_MEMORY_SCOPE_AGENT);
      }
    }
    float hprev = 0.f;
    unsigned phase = 1;
    __syncthreads();
    if (tid == 0)
      __hip_atomic_store(&flags1[wg * 16], phase, __ATOMIC_RELEASE, __HIP_MEMORY_SCOPE_AGENT);
    if (wave == 0)
      for (;;) {
        unsigned v = __hip_atomic_load(&flags1[lane * 16], __ATOMIC_RELAXED, __HIP_MEMORY_SCOPE_AGENT);
        if (__ballot(v >= phase) == ~0ull) break;
      }
    __syncthreads();

    for (int t = 0; t < T_SEQ; ++t) {
      // wait: h1[t] complete <=> all flags0 >= t+2 (layer 0 runs ahead; usually satisfied)
      if (wave == 0) {
        unsigned need = (unsigned)(t + 2);
        for (;;) {
          unsigned v = __hip_atomic_load(&flags0[lane * 16], __ATOMIC_RELAXED, __HIP_MEMORY_SCOPE_AGENT);
          if (__ballot(v >= need) == ~0ull) break;
        }
      }
      __syncthreads();
#pragma unroll
      for (int r = 0; r < 8; ++r) {
        int idx = r * 256 + tid;
        int b = idx >> 7, li = idx & 127;
        gld16(&hsA[b * 1032 + li * 8], h1seq + ((size_t)b * TP1 + t + 1) * HDIM + li * 8);
        gld16(&hsB[b * 1032 + li * 8], h2seq + ((size_t)b * TP1 + t) * HDIM + li * 8);
      }
      __syncthreads();

      f32x4 x0 = {0.f,0.f,0.f,0.f}, x1 = {0.f,0.f,0.f,0.f}, x2 = {0.f,0.f,0.f,0.f};
      f32x4 h0 = {0.f,0.f,0.f,0.f}, h1a = {0.f,0.f,0.f,0.f}, h2a = {0.f,0.f,0.f,0.f};
#pragma unroll
      for (int s = 0; s < 8; ++s) {
        short8 af1 = *(const short8*)&hsA[l16 * 1032 + kbase + s * 32 + quad * 8];
        short8 af2 = *(const short8*)&hsB[l16 * 1032 + kbase + s * 32 + quad * 8];
        x0 = __builtin_amdgcn_mfma_f32_16x16x32_bf16(af1, wfX[0][s], x0, 0, 0, 0);
        x1 = __builtin_amdgcn_mfma_f32_16x16x32_bf16(af1, wfX[1][s], x1, 0, 0, 0);
        x2 = __builtin_amdgcn_mfma_f32_16x16x32_bf16(af1, wfX[2][s], x2, 0, 0, 0);
        h0 = __builtin_amdgcn_mfma_f32_16x16x32_bf16(af2, wfH[0][s], h0, 0, 0, 0);
        h1a = __builtin_amdgcn_mfma_f32_16x16x32_bf16(af2, wfH[1][s], h1a, 0, 0, 0);
        h2a = __builtin_amdgcn_mfma_f32_16x16x32_bf16(af2, wfH[2][s], h2a, 0, 0, 0);
      }
#pragma unroll
      for (int r = 0; r < 4; ++r) {
        int o = (quad * 4 + r) * 16 + l16;
        part[wave][0][o] = x0[r];  part[wave][1][o] = x1[r];  part[wave][2][o] = x2[r];
        part[wave][3][o] = h0[r];  part[wave][4][o] = h1a[r]; part[wave][5][o] = h2a[r];
      }
      __syncthreads();

      float sxr = part[0][0][tid] + part[1][0][tid] + part[2][0][tid] + part[3][0][tid] + biasS[0][0][ej];
      float sxz = part[0][1][tid] + part[1][1][tid] + part[2][1][tid] + part[3][1][tid] + biasS[0][1][ej];
      float sxn = part[0][2][tid] + part[1][2][tid] + part[2][2][tid] + part[3][2][tid] + biasS[0][2][ej];
      float shr = part[0][3][tid] + part[1][3][tid] + part[2][3][tid] + part[3][3][tid] + biasS[1][0][ej];
      float shz = part[0][4][tid] + part[1][4][tid] + part[2][4][tid] + part[3][4][tid] + biasS[1][1][ej];
      float shn = part[0][5][tid] + part[1][5][tid] + part[2][5][tid] + part[3][5][tid] + biasS[1][2][ej];
      float r_ = 1.f / (1.f + __expf(-(sxr + shr)));
      float z_ = 1.f / (1.f + __expf(-(sxz + shz)));
      float pre = fminf(fmaxf(sxn + r_ * shn, -15.f), 15.f);
      float e2 = __expf(2.f * pre);
      float n_ = (e2 - 1.f) / (e2 + 1.f);
      float hn = (1.f - z_) * n_ + z_ * hprev;
      hprev = hn;

      unsigned mine = (unsigned)f2bf(hn);
      unsigned other = __shfl_xor(mine, 1);
      if ((tid & 1) == 0) {
        unsigned pk = mine | (other << 16);
        __hip_atomic_store((unsigned*)(h2seq + ((size_t)eb * TP1 + t + 1) * HDIM + j0 + ej), pk,
                           __ATOMIC_RELAXED, __HIP_MEMORY_SCOPE_AGENT);
      }
      ++phase;  // = t+2
      __syncthreads();  // drain h2 stores
      if (tid == 0)
        __hip_atomic_store(&flags1[wg * 16], phase, __ATOMIC_RELEASE, __HIP_MEMORY_SCOPE_AGENT);
      if (wave == 0)
        for (;;) {
          unsigned v = __hip_atomic_load(&flags1[lane * 16], __ATOMIC_RELAXED, __HIP_MEMORY_SCOPE_AGENT);
          if (__ballot(v >= phase) == ~0ull) break;
        }
      __syncthreads();
    }
  }
}

// ---------------- log_softmax over axis=1 (T): grid (16 b, 8 cgroups) ----------
__global__ void logsoftmax_kernel(float* __restrict__ out) {
  int b = blockIdx.x, cg = blockIdx.y;
  int ci = threadIdx.x & 15, ts = threadIdx.x >> 4;   // 16 cols x 16 t-strips
  int c = cg * 16 + ci;
  float m = -1e30f, s = 0.f;
  for (int t = ts; t < T_SEQ; t += 16) {
    float v = out[((size_t)b * T_SEQ + t) * 128 + c];
    if (v > m) { s = s * __expf(m - v) + 1.f; m = v; }
    else s += __expf(v - m);
  }
  __shared__ float mS[16][16], sS[16][16];
  mS[ts][ci] = m; sS[ts][ci] = s;
  __syncthreads();
  if (ts == 0) {
    float M = mS[0][ci], S = sS[0][ci];
#pragma unroll
    for (int k = 1; k < 16; ++k) {
      float m2 = mS[k][ci], s2 = sS[k][ci];
      float nm = fmaxf(M, m2);
      S = S * __expf(M - nm) + s2 * __expf(m2 - nm);
      M = nm;
    }
    sS[0][ci] = M + logf(S);
  }
  __syncthreads();
  float lsd = sS[0][ci];
  for (int t = ts; t < T_SEQ; t += 16) {
    size_t i = ((size_t)b * T_SEQ + t) * 128 + c;
    out[i] -= lsd;
  }
}

// --------------------------------------------------------------------------------
extern "C" void kernel_launch(void* const* d_in, const int* in_sizes, int n_in,
                              void* d_out, int out_size, void* d_ws, size_t ws_size,
                              hipStream_t stream) {
  const int*   tokens = (const int*)d_in[0];
  const float* emb  = (const float*)d_in[1];
  const float* Wih0 = (const float*)d_in[2];
  const float* Whh0 = (const float*)d_in[3];
  const float* bih0 = (const float*)d_in[4];
  const float* bhh0 = (const float*)d_in[5];
  const float* Wih1 = (const float*)d_in[6];
  const float* Whh1 = (const float*)d_in[7];
  const float* bih1 = (const float*)d_in[8];
  const float* bhh1 = (const float*)d_in[9];
  const float* Wlin = (const float*)d_in[10];
  const float* blin = (const float*)d_in[11];
  float* out = (float*)d_out;

  uint8_t* ws = (uint8_t*)d_ws;
  size_t off = 0;
  auto alloc = [&](size_t bytes) -> void* {
    void* p = ws + off;
    off += (bytes + 255) & ~(size_t)255;
    return p;
  };
  u16* h1seq = (u16*)alloc((size_t)16 * TP1 * HDIM * 2);  // also holds x_bf pre-scan
  u16* h2seq = (u16*)alloc((size_t)16 * TP1 * HDIM * 2);
  u16* gxbuf = (u16*)alloc((size_t)16384 * NG * 2);       // layer-0 input gates
  u16* wih0b = (u16*)alloc((size_t)NG * HDIM * 2);
  u16* whh0b = (u16*)alloc((size_t)NG * HDIM * 2);
  u16* wih1b = (u16*)alloc((size_t)NG * HDIM * 2);
  u16* whh1b = (u16*)alloc((size_t)NG * HDIM * 2);
  u16* wlinb = (u16*)alloc((size_t)128 * HDIM * 2);
  unsigned* flags = (unsigned*)alloc(8192);   // flags0 = [0..1023], flags1 = [1024..2047]

  cast5_kernel<<<dim3(12416), dim3(256), 0, stream>>>(
      Wih0, Whh0, Wih1, Whh1, Wlin, wih0b, whh0b, wih1b, whh1b, wlinb, flags);
  gather_cast_kernel<<<dim3(16384), dim3(256), 0, stream>>>(tokens, emb, h1seq);
  // gx0 = x @ W_ih0^T
  gemm_bt<true, false, false><<<dim3(128, 24), dim3(256), 0, stream>>>(
      h1seq, wih0b, gxbuf, nullptr, 16384, NG);
  // fused 2-layer scan (layer-1 computes its input gates in-scan from h1)
  fused_scan_kernel<<<dim3(128), dim3(256), 0, stream>>>(
      gxbuf, h1seq, h2seq, whh0b, wih1b, whh1b, bih0, bhh0, bih1, bhh1,
      flags, flags + 1024);
  // logits = h2 @ W_lin^T + b_lin -> d_out (fp32)
  gemm_bt<false, true, true><<<dim3(128, 1), dim3(256), 0, stream>>>(
      h2seq, wlinb, out, blin, 16384, 128);
  // log_softmax over T, in place
  logsoftmax_kernel<<<dim3(16, 8), dim3(256), 0, stream>>>(out);
}